// Round 3
// baseline (155.859 us; speedup 1.0000x reference)
//
#include <hip/hip_runtime.h>
#include <stdint.h>

#define BATCH 128
#define HH 14
#define WW 14
#define CC 512
#define HW (HH * WW)      // 196
#define KM_ITERS 10       // reference runs ITERS+1 = 11 assignment steps

// native clang vector type: accepted by __builtin_nontemporal_store,
// same layout/alignment as float4.
typedef float fx4 __attribute__((ext_vector_type(4)));

// ---------------------------------------------------------------------------
// Kernel 1: max-pixel coordinates, split across 256 blocks so ALL 256 CUs
// stream the input (128-block version capped at ~3.15 TB/s = half the chip).
// Block = (batch, channel-half): 256 channels, 512 threads.
//   thread = (c_local = tid&255, h_half = tid>>8); each thread scans 7 rows,
//   then the two h-halves are combined in LDS with numpy first-index ties:
//     - within half: strict '>' keeps first h
//     - across halves: (b1 > b0) strict, so a tie picks half 0 (lower h)
//     - arg1: first w (ascending) where combined colmax == best
// ---------------------------------------------------------------------------
__global__ __launch_bounds__(512) void k_points(const float* __restrict__ x,
                                                float2* __restrict__ pts) {
    const int blk  = blockIdx.x;      // 0..255
    const int b    = blk >> 1;
    const int half = blk & 1;
    const int tid  = threadIdx.x;
    const int cl   = tid & 255;       // local channel 0..255
    const int hh   = tid >> 8;        // h-half: rows [0,7) or [7,14)

    __shared__ float s_col[2][256][WW];   // 28 KiB
    __shared__ float s_best[2][256];
    __shared__ int   s_arg0[2][256];

    const float* base = x + (size_t)b * HW * CC + half * 256 + cl;

    float colmax[WW];
#pragma unroll
    for (int w = 0; w < WW; ++w) colmax[w] = -INFINITY;

    float best = -INFINITY;
    int arg0 = 0;
    const int h0 = hh * 7;
    for (int h = h0; h < h0 + 7; ++h) {
        float rowmax = -INFINITY;
#pragma unroll
        for (int w = 0; w < WW; ++w) {
            float v = base[(size_t)(h * WW + w) * CC];
            rowmax = fmaxf(rowmax, v);
            colmax[w] = fmaxf(colmax[w], v);
        }
        if (rowmax > best) { best = rowmax; arg0 = h; }  // strict > keeps first h
    }

#pragma unroll
    for (int w = 0; w < WW; ++w) s_col[hh][cl][w] = colmax[w];
    s_best[hh][cl] = best;
    s_arg0[hh][cl] = arg0;
    __syncthreads();

    if (tid < 256) {
        const int c = tid;
        const float b0 = s_best[0][c], b1 = s_best[1][c];
        const float bb = fmaxf(b0, b1);
        const int a0 = (b1 > b0) ? s_arg0[1][c] : s_arg0[0][c];  // tie -> half 0

        int arg1 = -1;
#pragma unroll
        for (int w = 0; w < WW; ++w) {
            const float cm = fmaxf(s_col[0][c][w], s_col[1][c][w]);
            if (arg1 < 0 && cm == bb) arg1 = w;   // first w attaining max
        }
        pts[b * CC + half * 256 + c] = make_float2((float)arg1, (float)a0);
    }
}

// ---------------------------------------------------------------------------
// Kernel 2: k-means, K=2, 11 assignment steps with the reference's swapped
// centroid update. One wave per batch; lane owns 8 points (c = lane + 64*j).
// Bit-identical arithmetic to the verified version (_rn intrinsics, tie->0).
// Round 2 proved the global pts round-trip + extra launch costs ~0.08 us.
// ---------------------------------------------------------------------------
__global__ __launch_bounds__(64) void k_kmeans(const float2* __restrict__ pts,
                                               uint8_t* __restrict__ assign) {
    const int b = blockIdx.x;
    const int lane = threadIdx.x;

    float px[8], py[8];
#pragma unroll
    for (int j = 0; j < 8; ++j) {
        float2 p = pts[b * CC + lane + 64 * j];
        px[j] = p.x; py[j] = p.y;
    }

    // totals over all 512 points (exact integers)
    float totx = 0.f, toty = 0.f;
#pragma unroll
    for (int j = 0; j < 8; ++j) { totx += px[j]; toty += py[j]; }
#pragma unroll
    for (int s = 32; s >= 1; s >>= 1) {
        totx += __shfl_xor(totx, s);
        toty += __shfl_xor(toty, s);
    }

    // initial centroids = points of channels 0 and 1
    float c0x = __shfl(px[0], 0), c0y = __shfl(py[0], 0);
    float c1x = __shfl(px[0], 1), c1y = __shfl(py[0], 1);

    int a[8];
    for (int it = 0; it <= KM_ITERS; ++it) {
        float sx = 0.f, sy = 0.f, cnt = 0.f;
#pragma unroll
        for (int j = 0; j < 8; ++j) {
            float dx0 = __fsub_rn(px[j], c0x);
            float dy0 = __fsub_rn(py[j], c0y);
            float d0  = __fadd_rn(__fmul_rn(dx0, dx0), __fmul_rn(dy0, dy0));
            float dx1 = __fsub_rn(px[j], c1x);
            float dy1 = __fsub_rn(py[j], c1y);
            float d1  = __fadd_rn(__fmul_rn(dx1, dx1), __fmul_rn(dy1, dy1));
            a[j] = (d1 < d0) ? 1 : 0;   // argmin: tie -> cluster 0
            if (a[j]) { sx += px[j]; sy += py[j]; cnt += 1.f; }
        }
#pragma unroll
        for (int s = 32; s >= 1; s >>= 1) {
            sx  += __shfl_xor(sx, s);
            sy  += __shfl_xor(sy, s);
            cnt += __shfl_xor(cnt, s);
        }
        float cnt0 = (float)CC - cnt;           // exact
        c0x = __fdiv_rn(sx, fmaxf(cnt, 1.f));   // note the swap: c0 from m1
        c0y = __fdiv_rn(sy, fmaxf(cnt, 1.f));
        c1x = __fdiv_rn(totx - sx, fmaxf(cnt0, 1.f));  // exact int subtraction
        c1y = __fdiv_rn(toty - sy, fmaxf(cnt0, 1.f));
    }

#pragma unroll
    for (int j = 0; j < 8; ++j)
        assign[b * CC + lane + 64 * j] = (uint8_t)a[j];
}

// ---------------------------------------------------------------------------
// Kernel 3: scatter. One thread per float4 (4 channels). Mask loaded as one
// uint32 (4 assignment bytes). Writes C0 then C1 (concatenated in d_out).
// Output stores are non-temporal: outputs are never re-read, so keep the
// 102.8 MB write stream from evicting the input out of L2/L3 mid-kernel.
// (Unchanged from the passing round-2 version: one-variable A/B this round.)
// ---------------------------------------------------------------------------
#define N4 (BATCH * HW * (CC / 4))   // 3,211,264 float4 per output

__global__ __launch_bounds__(256) void k_scatter(const fx4* __restrict__ x4,
                                                 const uint32_t* __restrict__ am4,
                                                 fx4* __restrict__ out4) {
    const int idx = blockIdx.x * 256 + threadIdx.x;
    if (idx >= N4) return;
    const int c4  = idx & (CC / 4 - 1);   // 0..127
    const int pix = idx >> 7;             // b*196 + hw
    const int b   = pix / HW;

    const uint32_t m = am4[b * (CC / 4) + c4];
    const fx4 v = x4[idx];

    fx4 o0, o1;
    o0.x = (m & 0x000000ffu) ? 0.f : v.x;  o1.x = (m & 0x000000ffu) ? v.x : 0.f;
    o0.y = (m & 0x0000ff00u) ? 0.f : v.y;  o1.y = (m & 0x0000ff00u) ? v.y : 0.f;
    o0.z = (m & 0x00ff0000u) ? 0.f : v.z;  o1.z = (m & 0x00ff0000u) ? v.z : 0.f;
    o0.w = (m & 0xff000000u) ? 0.f : v.w;  o1.w = (m & 0xff000000u) ? v.w : 0.f;

    __builtin_nontemporal_store(o0, &out4[idx]);        // C0
    __builtin_nontemporal_store(o1, &out4[idx + N4]);   // C1
}

// ---------------------------------------------------------------------------
extern "C" void kernel_launch(void* const* d_in, const int* in_sizes, int n_in,
                              void* d_out, int out_size, void* d_ws, size_t ws_size,
                              hipStream_t stream) {
    const float* x = (const float*)d_in[0];

    float2*  pts    = (float2*)d_ws;                                        // 512 KiB
    uint8_t* assign = (uint8_t*)d_ws + (size_t)BATCH * CC * sizeof(float2); // 64 KiB

    k_points<<<2 * BATCH, 512, 0, stream>>>(x, pts);
    k_kmeans<<<BATCH, 64, 0, stream>>>(pts, (uint8_t*)assign);
    k_scatter<<<(N4 + 255) / 256, 256, 0, stream>>>(
        (const fx4*)x, (const uint32_t*)assign, (fx4*)d_out);
}